// Round 10
// baseline (552.961 us; speedup 1.0000x reference)
//
#include <hip/hip_runtime.h>
#include <hip/hip_bf16.h>

// out[b,o] = sum_n relu( (s[b]-v[n]) . W[n,o,:] + bias[n,o] )
//          = sum_n relu( s[b].W[n,o,:] + c[n,o] ),  c[n,o] = bias[n,o] - v[n].W[n,o,:]
//
// prep: per-(n, 64-o slab) LDS transpose of W -> bf16 fragment-order Wf
//   (1KB chunk per (n, oc16, kt); lane l holds the exact 16x16x32 B-fragment).
//   Also c = bias - v.W. Measured at its ~61us HBM floor.
// main: BM=64 x BO=64, TPB=512, 64KB LDS -> 2 blocks/CU -> 4 waves/SIMD.
//   r9 lesson: under the (512,4) cap the compiler shrank to 52 regs and
//   SERIALIZED the loads (load->wait->mfma). This round hand-pipelines:
//   2-stage register double-buffer (bqA/aqA vs bqB/aqB), prefetch issued
//   BEFORE the opposite set's 8 MFMAs and consumed a stage later -> values
//   live across the MFMA cluster -> ~110 regs, counted vmcnt waits.
// fused: fp32-W fallback if ws too small.

typedef __attribute__((ext_vector_type(8)))  short bf16x8;
typedef __attribute__((ext_vector_type(4)))  float f32x4;

constexpr int B   = 1024;
constexpr int N   = 64;
constexpr int D   = 512;
constexpr int OUT = 2048;

constexpr int BM  = 64;     // rows per block
constexpr int BO  = 64;     // cols per block: 4 og x 16
constexpr int TPB = 512;    // 8 waves

static __device__ __forceinline__ unsigned short f2bf(float f) {
    unsigned int u = __builtin_bit_cast(unsigned int, f);
    u += 0x7FFFu + ((u >> 16) & 1u);
    return (unsigned short)(u >> 16);
}

static __device__ __forceinline__ float bf2f(unsigned short u) {
    unsigned int x = ((unsigned int)u) << 16;
    return __builtin_bit_cast(float, x);
}

static __device__ __forceinline__ bf16x8 cvt8(float4 a, float4 b) {
    bf16x8 r;
    r[0] = (short)f2bf(a.x); r[1] = (short)f2bf(a.y);
    r[2] = (short)f2bf(a.z); r[3] = (short)f2bf(a.w);
    r[4] = (short)f2bf(b.x); r[5] = (short)f2bf(b.y);
    r[6] = (short)f2bf(b.z); r[7] = (short)f2bf(b.w);
    return r;
}

// ---------------- prep: Wf (16-col fragment-order) + c, via LDS transpose ----------------
__global__ __launch_bounds__(256) void prep_kernel(const float* __restrict__ W,
                                                   const float* __restrict__ V,
                                                   const float* __restrict__ bias,
                                                   unsigned short* __restrict__ Wf,
                                                   float* __restrict__ c) {
    __shared__ unsigned short L[64 * 512];   // 64 KiB, swizzled: kc ^ (r&15)

    const int nb = blockIdx.x;
    const int n  = nb >> 5;          // 0..63
    const int ob = nb & 31;          // 0..31
    const int t  = threadIdx.x;

    #pragma unroll
    for (int i = 0; i < 16; ++i) {
        const int cid = i * 256 + t;
        const int r   = cid >> 6;
        const int kc  = cid & 63;
        const float4* wp = reinterpret_cast<const float4*>(
            W + ((size_t)n * OUT + ob * 64 + r) * D + kc * 8);
        bf16x8 v8 = cvt8(wp[0], wp[1]);
        *reinterpret_cast<bf16x8*>(&L[r * 512 + ((kc ^ (r & 15)) * 8)]) = v8;
    }
    __syncthreads();

    if (t < 64) {
        const int r = t;
        float s = 0.f;
        #pragma unroll 8
        for (int kc = 0; kc < 64; ++kc) {
            bf16x8 wv = *reinterpret_cast<const bf16x8*>(&L[r * 512 + ((kc ^ (r & 15)) * 8)]);
            const float4 va = *reinterpret_cast<const float4*>(V + (size_t)n * D + kc * 8);
            const float4 vb = *reinterpret_cast<const float4*>(V + (size_t)n * D + kc * 8 + 4);
            s += bf2f((unsigned short)wv[0]) * va.x + bf2f((unsigned short)wv[1]) * va.y
               + bf2f((unsigned short)wv[2]) * va.z + bf2f((unsigned short)wv[3]) * va.w
               + bf2f((unsigned short)wv[4]) * vb.x + bf2f((unsigned short)wv[5]) * vb.y
               + bf2f((unsigned short)wv[6]) * vb.z + bf2f((unsigned short)wv[7]) * vb.w;
        }
        const int o = ob * 64 + r;
        c[n * OUT + o] = bias[n * OUT + o] - s;
    }

    const size_t obase = (size_t)(n * 128 + ob * 4) * 16 * 512;   // shorts
    #pragma unroll
    for (int i = 0; i < 16; ++i) {
        const int cid   = i * 256 + t;
        const int lane  = cid & 63;
        const int chunk = cid >> 6;          // og*16 + kt
        const int og    = chunk >> 4;
        const int kt    = chunk & 15;
        const int row   = og * 16 + (lane & 15);
        const int kc    = kt * 4 + (lane >> 4);
        bf16x8 v8 = *reinterpret_cast<const bf16x8*>(&L[row * 512 + ((kc ^ (row & 15)) * 8)]);
        *reinterpret_cast<bf16x8*>(&Wf[obase + (size_t)chunk * 512 + lane * 8]) = v8;
    }
}

// ---------------- main: 16x16x32 MFMA, 2 blocks/CU, reg-pipelined loads ----------------
__global__ __launch_bounds__(TPB, 4) void main_kernel(const float* __restrict__ S,
                                                      const unsigned short* __restrict__ Wf,
                                                      const float* __restrict__ C,
                                                      float* __restrict__ out) {
    __shared__ unsigned short As[BM * D];   // 64 KiB

    const int bid = blockIdx.x;
    const int ob  = (bid & 7) + 8 * ((bid >> 7) & 3);   // 0..31, XCD-pinned
    const int bm0 = ((bid >> 3) & 15) * BM;

    const int t    = threadIdx.x;
    const int lane = t & 63;
    const int w    = t >> 6;          // 0..7
    const int og   = w & 3;           // 16-col group
    const int mg   = w >> 2;          // 32-row group
    const int l15  = lane & 15;
    const int lg   = lane >> 4;       // 0..3
    const int ocol = ob * BO + og * 16 + l15;
    const int rb   = mg * 32;

    // ---- stage A (once) ----
    #pragma unroll
    for (int i = 0; i < (BM * D / 8) / TPB; ++i) {
        int cid = i * TPB + t;
        int row = cid >> 6;
        int kc  = cid & 63;
        const float4* sp = reinterpret_cast<const float4*>(S + (size_t)(bm0 + row) * D + kc * 8);
        bf16x8 val = cvt8(sp[0], sp[1]);
        *reinterpret_cast<bf16x8*>(&As[row * D + ((kc ^ (row & 15)) * 8)]) = val;
    }
    __syncthreads();

    f32x4 oacc[2];
    #pragma unroll
    for (int mi = 0; mi < 2; ++mi) oacc[mi] = (f32x4){0.f, 0.f, 0.f, 0.f};

    constexpr size_t NSTR = (size_t)128 * 16 * 512;   // per-n stride in shorts

    const int r0 = rb + l15;
    const int r1 = rb + 16 + l15;
    const unsigned short* a0 = &As[r0 * D];
    const unsigned short* a1 = &As[r1 * D];

    for (int nc = 0; nc < 16; ++nc) {
        const int n0 = nc * 4;

        f32x4 pre[4][2];
        #pragma unroll
        for (int j = 0; j < 4; ++j)
            #pragma unroll
            for (int mi = 0; mi < 2; ++mi) pre[j][mi] = (f32x4){0.f, 0.f, 0.f, 0.f};

        const unsigned short* wf0 =
            Wf + (size_t)(n0 * 128 + ob * 4 + og) * 16 * 512 + lane * 8;

        // ---- prologue: load ks=0 set ----
        bf16x8 bqA0 = *reinterpret_cast<const bf16x8*>(wf0 + 0 * NSTR);
        bf16x8 bqA1 = *reinterpret_cast<const bf16x8*>(wf0 + 1 * NSTR);
        bf16x8 bqA2 = *reinterpret_cast<const bf16x8*>(wf0 + 2 * NSTR);
        bf16x8 bqA3 = *reinterpret_cast<const bf16x8*>(wf0 + 3 * NSTR);
        bf16x8 aqA0 = *reinterpret_cast<const bf16x8*>(a0 + ((lg ^ l15) * 8));
        bf16x8 aqA1 = *reinterpret_cast<const bf16x8*>(a1 + ((lg ^ l15) * 8));

        #pragma unroll
        for (int ks = 0; ks < 16; ks += 2) {
            // prefetch ks+1 set (B) before A-set MFMAs
            const int k1 = ks + 1;
            bf16x8 bqB0 = *reinterpret_cast<const bf16x8*>(wf0 + 0 * NSTR + k1 * 512);
            bf16x8 bqB1 = *reinterpret_cast<const bf16x8*>(wf0 + 1 * NSTR + k1 * 512);
            bf16x8 bqB2 = *reinterpret_cast<const bf16x8*>(wf0 + 2 * NSTR + k1 * 512);
            bf16x8 bqB3 = *reinterpret_cast<const bf16x8*>(wf0 + 3 * NSTR + k1 * 512);
            const int kc1 = k1 * 4 + lg;
            bf16x8 aqB0 = *reinterpret_cast<const bf16x8*>(a0 + ((kc1 ^ l15) * 8));
            bf16x8 aqB1 = *reinterpret_cast<const bf16x8*>(a1 + ((kc1 ^ l15) * 8));

            pre[0][0] = __builtin_amdgcn_mfma_f32_16x16x32_bf16(aqA0, bqA0, pre[0][0], 0, 0, 0);
            pre[0][1] = __builtin_amdgcn_mfma_f32_16x16x32_bf16(aqA1, bqA0, pre[0][1], 0, 0, 0);
            pre[1][0] = __builtin_amdgcn_mfma_f32_16x16x32_bf16(aqA0, bqA1, pre[1][0], 0, 0, 0);
            pre[1][1] = __builtin_amdgcn_mfma_f32_16x16x32_bf16(aqA1, bqA1, pre[1][1], 0, 0, 0);
            pre[2][0] = __builtin_amdgcn_mfma_f32_16x16x32_bf16(aqA0, bqA2, pre[2][0], 0, 0, 0);
            pre[2][1] = __builtin_amdgcn_mfma_f32_16x16x32_bf16(aqA1, bqA2, pre[2][1], 0, 0, 0);
            pre[3][0] = __builtin_amdgcn_mfma_f32_16x16x32_bf16(aqA0, bqA3, pre[3][0], 0, 0, 0);
            pre[3][1] = __builtin_amdgcn_mfma_f32_16x16x32_bf16(aqA1, bqA3, pre[3][1], 0, 0, 0);

            // prefetch ks+2 set back into A (wrap keeps LDS index in-bounds;
            // the wrapped load at the last step is dead but harmless)
            const int k2 = (ks + 2) & 15;
            bqA0 = *reinterpret_cast<const bf16x8*>(wf0 + 0 * NSTR + k2 * 512);
            bqA1 = *reinterpret_cast<const bf16x8*>(wf0 + 1 * NSTR + k2 * 512);
            bqA2 = *reinterpret_cast<const bf16x8*>(wf0 + 2 * NSTR + k2 * 512);
            bqA3 = *reinterpret_cast<const bf16x8*>(wf0 + 3 * NSTR + k2 * 512);
            const int kc2 = k2 * 4 + lg;
            aqA0 = *reinterpret_cast<const bf16x8*>(a0 + ((kc2 ^ l15) * 8));
            aqA1 = *reinterpret_cast<const bf16x8*>(a1 + ((kc2 ^ l15) * 8));

            pre[0][0] = __builtin_amdgcn_mfma_f32_16x16x32_bf16(aqB0, bqB0, pre[0][0], 0, 0, 0);
            pre[0][1] = __builtin_amdgcn_mfma_f32_16x16x32_bf16(aqB1, bqB0, pre[0][1], 0, 0, 0);
            pre[1][0] = __builtin_amdgcn_mfma_f32_16x16x32_bf16(aqB0, bqB1, pre[1][0], 0, 0, 0);
            pre[1][1] = __builtin_amdgcn_mfma_f32_16x16x32_bf16(aqB1, bqB1, pre[1][1], 0, 0, 0);
            pre[2][0] = __builtin_amdgcn_mfma_f32_16x16x32_bf16(aqB0, bqB2, pre[2][0], 0, 0, 0);
            pre[2][1] = __builtin_amdgcn_mfma_f32_16x16x32_bf16(aqB1, bqB2, pre[2][1], 0, 0, 0);
            pre[3][0] = __builtin_amdgcn_mfma_f32_16x16x32_bf16(aqB0, bqB3, pre[3][0], 0, 0, 0);
            pre[3][1] = __builtin_amdgcn_mfma_f32_16x16x32_bf16(aqB1, bqB3, pre[3][1], 0, 0, 0);
        }

        #pragma unroll
        for (int j = 0; j < 4; ++j) {
            const float cv = C[(n0 + j) * OUT + ocol];
            #pragma unroll
            for (int mi = 0; mi < 2; ++mi)
                #pragma unroll
                for (int r = 0; r < 4; ++r)
                    oacc[mi][r] += fmaxf(pre[j][mi][r] + cv, 0.f);
        }
    }

    #pragma unroll
    for (int mi = 0; mi < 2; ++mi) {
        #pragma unroll
        for (int q = 0; q < 4; ++q) {
            const int row = bm0 + rb + mi * 16 + lg * 4 + q;
            out[(size_t)row * OUT + ocol] = oacc[mi][q];
        }
    }
}

// ---------------- fallback: fused fp32-W kernel (r2-proven) ----------------
__global__ __launch_bounds__(512) void fused_kernel(const float* __restrict__ S,
                                                    const float* __restrict__ W,
                                                    const float* __restrict__ V,
                                                    const float* __restrict__ bias,
                                                    float* __restrict__ out) {
    __shared__ unsigned short As3[128 * D];

    const int t    = threadIdx.x;
    const int lane = t & 63;
    const int w    = t >> 6;
    const int og   = w & 3;
    const int ngh  = w >> 2;
    const int l15  = lane & 15;
    const int lg   = lane >> 4;
    const int ob0  = blockIdx.x * 64;
    const int bm0  = blockIdx.y * 128;
    const int ocol = ob0 + og * 16 + l15;

    #pragma unroll
    for (int i = 0; i < (128 * D / 8) / 512; ++i) {
        int cid = i * 512 + t;
        int row = cid >> 6;
        int kc  = cid & 63;
        const float4* sp = reinterpret_cast<const float4*>(S + (size_t)(bm0 + row) * D + kc * 8);
        bf16x8 val = cvt8(sp[0], sp[1]);
        *reinterpret_cast<bf16x8*>(&As3[row * D + ((kc ^ (row & 7)) * 8)]) = val;
    }
    __syncthreads();

    f32x4 oacc[8];
    #pragma unroll
    for (int mi = 0; mi < 8; ++mi) oacc[mi] = (f32x4){0.f, 0.f, 0.f, 0.f};

    const int kofs = lg * 8;

    for (int nc = 0; nc < 8; ++nc) {
        const int n0 = ngh * 32 + nc * 4;

        f32x4 pre[4][8];
        #pragma unroll
        for (int j = 0; j < 4; ++j)
            #pragma unroll
            for (int mi = 0; mi < 8; ++mi) pre[j][mi] = (f32x4){0.f, 0.f, 0.f, 0.f};

        float cacc[4] = {0.f, 0.f, 0.f, 0.f};

        const float* wbase = W + ((size_t)n0 * OUT + ocol) * D + kofs;
        const float* vbase = V + (size_t)n0 * D + kofs;

        #pragma unroll 2
        for (int ks = 0; ks < 16; ++ks) {
            bf16x8 bq[4];
            #pragma unroll
            for (int j = 0; j < 4; ++j) {
                const float* wr = wbase + (size_t)j * (OUT * D) + ks * 32;
                float4 wa = *reinterpret_cast<const float4*>(wr);
                float4 wb = *reinterpret_cast<const float4*>(wr + 4);
                const float* vr = vbase + (size_t)j * D + ks * 32;
                float4 va = *reinterpret_cast<const float4*>(vr);
                float4 vb = *reinterpret_cast<const float4*>(vr + 4);
                cacc[j] += wa.x * va.x + wa.y * va.y + wa.z * va.z + wa.w * va.w
                         + wb.x * vb.x + wb.y * vb.y + wb.z * vb.z + wb.w * vb.w;
                bq[j] = cvt8(wa, wb);
            }
            const int kc = ks * 4 + lg;
            #pragma unroll
            for (int mi = 0; mi < 8; ++mi) {
                const int row = mi * 16 + l15;
                bf16x8 aq = *reinterpret_cast<const bf16x8*>(
                    &As3[row * D + ((kc ^ (row & 7)) * 8)]);
                pre[0][mi] = __builtin_amdgcn_mfma_f32_16x16x32_bf16(aq, bq[0], pre[0][mi], 0, 0, 0);
                pre[1][mi] = __builtin_amdgcn_mfma_f32_16x16x32_bf16(aq, bq[1], pre[1][mi], 0, 0, 0);
                pre[2][mi] = __builtin_amdgcn_mfma_f32_16x16x32_bf16(aq, bq[2], pre[2][mi], 0, 0, 0);
                pre[3][mi] = __builtin_amdgcn_mfma_f32_16x16x32_bf16(aq, bq[3], pre[3][mi], 0, 0, 0);
            }
        }

        #pragma unroll
        for (int j = 0; j < 4; ++j) {
            float cs = cacc[j];
            cs += __shfl_xor(cs, 16);
            cs += __shfl_xor(cs, 32);
            const float cv = bias[(n0 + j) * OUT + ocol] - cs;
            #pragma unroll
            for (int mi = 0; mi < 8; ++mi)
                #pragma unroll
                for (int r = 0; r < 4; ++r)
                    oacc[mi][r] += fmaxf(pre[j][mi][r] + cv, 0.f);
        }
    }

    __syncthreads();
    float* red = reinterpret_cast<float*>(As3);
    if (ngh == 1) {
        #pragma unroll
        for (int mi = 0; mi < 8; ++mi)
            *reinterpret_cast<f32x4*>(&red[(og * 8 + mi) * 256 + lane * 4]) = oacc[mi];
    }
    __syncthreads();
    if (ngh == 0) {
        #pragma unroll
        for (int mi = 0; mi < 8; ++mi) {
            f32x4 o2 = *reinterpret_cast<const f32x4*>(&red[(og * 8 + mi) * 256 + lane * 4]);
            #pragma unroll
            for (int r = 0; r < 4; ++r) {
                int row = bm0 + mi * 16 + lg * 4 + r;
                out[(size_t)row * OUT + ocol] = oacc[mi][r] + o2[r];
            }
        }
    }
}

extern "C" void kernel_launch(void* const* d_in, const int* in_sizes, int n_in,
                              void* d_out, int out_size, void* d_ws, size_t ws_size,
                              hipStream_t stream) {
    const float* S    = (const float*)d_in[0];   // semantic_vec [B, D]
    const float* V    = (const float*)d_in[1];   // vertices     [N, D]
    const float* W    = (const float*)d_in[2];   // W            [N, OUT, D]
    const float* bias = (const float*)d_in[3];   // b            [N, OUT]
    float* out = (float*)d_out;                  // [B, OUT] f32

    const size_t wb_bytes = (size_t)N * OUT * D * sizeof(unsigned short); // 128 MiB
    const size_t c_bytes  = (size_t)N * OUT * sizeof(float);              // 512 KiB

    if (ws_size >= wb_bytes + c_bytes) {
        unsigned short* Wf = (unsigned short*)d_ws;
        float*          c  = (float*)((char*)d_ws + wb_bytes);
        prep_kernel<<<dim3(N * 32), dim3(256), 0, stream>>>(W, V, bias, Wf, c);
        main_kernel<<<dim3((OUT / BO) * (B / BM)), dim3(TPB), 0, stream>>>(S, Wf, c, out);
    } else {
        fused_kernel<<<dim3(OUT / 64, B / 128), dim3(512), 0, stream>>>(S, W, V, bias, out);
    }
}

// Round 11
// 315.201 us; speedup vs baseline: 1.7543x; 1.7543x over previous
//
#include <hip/hip_runtime.h>
#include <hip/hip_bf16.h>

// out[b,o] = sum_n relu( (s[b]-v[n]) . W[n,o,:] + bias[n,o] )
//          = sum_n relu( s[b].W[n,o,:] + c[n,o] ),  c[n,o] = bias[n,o] - v[n].W[n,o,:]
//
// prep: per-(n, 64-o slab) LDS transpose -> bf16 fragment-order Wswz:
//   1KB chunk per (n, ob, ks, og); lane l holds the exact 32x32x16 B-fragment
//   (o = ob*64+og*32+(l&31), k = ks*16+(l>>5)*8). Also c = bias - v.W.
// main: 32x32x16 MFMA, BM=128 x BO=64, 8 waves = og(2) x mg(2) x ng(2).
//   128KB A-tile -> 1 block/CU -> 2 waves/SIMD -> up to 256 VGPR are FREE.
//   __launch_bounds__(512,2) tells the allocator exactly that (permissive cap;
//   r7's 120-reg allocation rotated the j-loop and doubled LDS reads).
//   pre[2][2]+oacc[2] = 96 acc regs -> ~150 total demand, ~100 headroom for
//   the compiler's own load pipelining. Coalesced 1KB W streams; mg-duplicate
//   waves share via L1. 2-way n-reduction through LDS; bm-blocks of one ob
//   land on one XCD (bid%8 == ob%8) for W L2 sharing.
// fused: fp32-W fallback if ws too small.
//
// LESSON (r4/r5/r9/r10): never use launch_bounds min-waves to RESTRICT regs
// below accumulator demand -- the allocator snaps to a tier and spills.

typedef __attribute__((ext_vector_type(8)))  short bf16x8;
typedef __attribute__((ext_vector_type(4)))  float f32x4;
typedef __attribute__((ext_vector_type(16))) float f32x16;

constexpr int B   = 1024;
constexpr int N   = 64;
constexpr int D   = 512;
constexpr int OUT = 2048;

constexpr int BM  = 128;    // rows per block
constexpr int BO  = 64;     // cols per block: 2 og x 32
constexpr int TPB = 512;    // 8 waves

static __device__ __forceinline__ unsigned short f2bf(float f) {
    unsigned int u = __builtin_bit_cast(unsigned int, f);
    u += 0x7FFFu + ((u >> 16) & 1u);
    return (unsigned short)(u >> 16);
}

static __device__ __forceinline__ float bf2f(unsigned short u) {
    unsigned int x = ((unsigned int)u) << 16;
    return __builtin_bit_cast(float, x);
}

static __device__ __forceinline__ bf16x8 cvt8(float4 a, float4 b) {
    bf16x8 r;
    r[0] = (short)f2bf(a.x); r[1] = (short)f2bf(a.y);
    r[2] = (short)f2bf(a.z); r[3] = (short)f2bf(a.w);
    r[4] = (short)f2bf(b.x); r[5] = (short)f2bf(b.y);
    r[6] = (short)f2bf(b.z); r[7] = (short)f2bf(b.w);
    return r;
}

// ---------------- prep: Wswz (32-col fragment-order) + c, via LDS transpose ----------------
// grid = N * 32 blocks (one per (n, 64-o slab)), 256 threads.
__global__ __launch_bounds__(256) void prep_kernel(const float* __restrict__ W,
                                                   const float* __restrict__ V,
                                                   const float* __restrict__ bias,
                                                   unsigned short* __restrict__ Wswz,
                                                   float* __restrict__ c) {
    __shared__ unsigned short L[64 * 512];   // 64 KiB, swizzled: kc ^ (r&15)

    const int nb = blockIdx.x;
    const int n  = nb >> 5;          // 0..63
    const int ob = nb & 31;          // 0..31
    const int t  = threadIdx.x;

    #pragma unroll
    for (int i = 0; i < 16; ++i) {
        const int cid = i * 256 + t;
        const int r   = cid >> 6;
        const int kc  = cid & 63;
        const float4* wp = reinterpret_cast<const float4*>(
            W + ((size_t)n * OUT + ob * 64 + r) * D + kc * 8);
        bf16x8 v8 = cvt8(wp[0], wp[1]);
        *reinterpret_cast<bf16x8*>(&L[r * 512 + ((kc ^ (r & 15)) * 8)]) = v8;
    }
    __syncthreads();

    if (t < 64) {
        const int r = t;
        float s = 0.f;
        #pragma unroll 8
        for (int kc = 0; kc < 64; ++kc) {
            bf16x8 wv = *reinterpret_cast<const bf16x8*>(&L[r * 512 + ((kc ^ (r & 15)) * 8)]);
            const float4 va = *reinterpret_cast<const float4*>(V + (size_t)n * D + kc * 8);
            const float4 vb = *reinterpret_cast<const float4*>(V + (size_t)n * D + kc * 8 + 4);
            s += bf2f((unsigned short)wv[0]) * va.x + bf2f((unsigned short)wv[1]) * va.y
               + bf2f((unsigned short)wv[2]) * va.z + bf2f((unsigned short)wv[3]) * va.w
               + bf2f((unsigned short)wv[4]) * vb.x + bf2f((unsigned short)wv[5]) * vb.y
               + bf2f((unsigned short)wv[6]) * vb.z + bf2f((unsigned short)wv[7]) * vb.w;
        }
        const int o = ob * 64 + r;
        c[n * OUT + o] = bias[n * OUT + o] - s;
    }

    // fragment-order chunks: chunk(n,ob,ks,og) = (n*32+ob)*64 + ks*2 + og.
    const size_t obase = ((size_t)(n * 32 + ob) * 64) * 512;
    #pragma unroll
    for (int i = 0; i < 16; ++i) {
        const int cid   = i * 256 + t;
        const int lane  = cid & 63;
        const int chunk = cid >> 6;          // ks*2 + og
        const int og    = chunk & 1;
        const int ks    = chunk >> 1;
        const int row   = og * 32 + (lane & 31);
        const int kc    = ks * 2 + (lane >> 5);
        bf16x8 v8 = *reinterpret_cast<const bf16x8*>(&L[row * 512 + ((kc ^ (row & 15)) * 8)]);
        *reinterpret_cast<bf16x8*>(&Wswz[obase + (size_t)chunk * 512 + lane * 8]) = v8;
    }
}

// ---------------- main: 32x32x16 MFMA, generous reg budget, no rotation ----------------
__global__ __launch_bounds__(TPB, 2) void main_kernel(const float* __restrict__ S,
                                                      const unsigned short* __restrict__ Wswz,
                                                      const float* __restrict__ C,
                                                      float* __restrict__ out) {
    // A-tile: 128 x 512 bf16, XOR-swizzled 16B chunks: kc ^ (row&15).
    __shared__ unsigned short As[BM * D];   // 128 KiB

    const int t    = threadIdx.x;
    const int lane = t & 63;
    const int w    = t >> 6;          // 0..7
    const int og   = w & 1;           // 32-col group
    const int mg   = (w >> 1) & 1;    // 64-row group
    const int ng   = w >> 2;          // n-half
    const int oc   = lane & 31;
    const int hi   = lane >> 5;       // k-half selector
    const int ob   = blockIdx.x;      // 0..31 ; bid%8 == ob%8 -> XCD pinning
    const int bm0  = blockIdx.y * BM;
    const int ocol = ob * BO + og * 32 + oc;

    // ---- stage A (once per block) ----
    #pragma unroll
    for (int i = 0; i < (BM * D / 8) / TPB; ++i) {   // 16 iters
        int cid = i * TPB + t;
        int row = cid >> 6;
        int kc  = cid & 63;
        const float4* sp = reinterpret_cast<const float4*>(S + (size_t)(bm0 + row) * D + kc * 8);
        bf16x8 val = cvt8(sp[0], sp[1]);
        *reinterpret_cast<bf16x8*>(&As[row * D + ((kc ^ (row & 15)) * 8)]) = val;
    }
    __syncthreads();

    f32x16 oacc[2];
    #pragma unroll
    for (int mi = 0; mi < 2; ++mi)
        #pragma unroll
        for (int r = 0; r < 16; ++r) oacc[mi][r] = 0.f;

    const int r0 = mg * 64 + oc;        // mi=0 row
    const int r1 = mg * 64 + 32 + oc;   // mi=1 row

    for (int nc = 0; nc < 16; ++nc) {
        const int n0 = ng * 32 + nc * 2;

        f32x16 pre[2][2];
        #pragma unroll
        for (int j = 0; j < 2; ++j)
            #pragma unroll
            for (int mi = 0; mi < 2; ++mi)
                #pragma unroll
                for (int r = 0; r < 16; ++r) pre[j][mi][r] = 0.f;

        // coalesced 1KB-chunk streams; n0+1 is +2 MiB (32*64 chunks).
        const unsigned short* wb0 =
            Wswz + ((size_t)(n0 * 32 + ob) * 64 + og) * 512 + lane * 8;
        const unsigned short* wb1 = wb0 + (size_t)2048 * 512;

        #pragma unroll 4
        for (int ks = 0; ks < 32; ++ks) {           // K-steps of 16
            bf16x8 bq0 = *reinterpret_cast<const bf16x8*>(wb0 + ks * 1024);
            bf16x8 bq1 = *reinterpret_cast<const bf16x8*>(wb1 + ks * 1024);
            const int kc2 = ks * 2 + hi;            // 16B chunk index along k
            bf16x8 aq0 = *reinterpret_cast<const bf16x8*>(
                &As[r0 * D + ((kc2 ^ (r0 & 15)) * 8)]);
            bf16x8 aq1 = *reinterpret_cast<const bf16x8*>(
                &As[r1 * D + ((kc2 ^ (r1 & 15)) * 8)]);

            pre[0][0] = __builtin_amdgcn_mfma_f32_32x32x16_bf16(aq0, bq0, pre[0][0], 0, 0, 0);
            pre[0][1] = __builtin_amdgcn_mfma_f32_32x32x16_bf16(aq1, bq0, pre[0][1], 0, 0, 0);
            pre[1][0] = __builtin_amdgcn_mfma_f32_32x32x16_bf16(aq0, bq1, pre[1][0], 0, 0, 0);
            pre[1][1] = __builtin_amdgcn_mfma_f32_32x32x16_bf16(aq1, bq1, pre[1][1], 0, 0, 0);
        }

        #pragma unroll
        for (int j = 0; j < 2; ++j) {
            const float cv = C[(n0 + j) * OUT + ocol];
            #pragma unroll
            for (int mi = 0; mi < 2; ++mi)
                #pragma unroll
                for (int r = 0; r < 16; ++r)
                    oacc[mi][r] += fmaxf(pre[j][mi][r] + cv, 0.f);
        }
    }

    // ---- 2-way cross n-half reduction through LDS, then store ----
    // Slab per (mg,og): 2048 f32 (8 KiB); 4 slabs = 32 KiB, conflict-free.
    __syncthreads();                      // everyone done reading As
    float* red = reinterpret_cast<float*>(As);
    if (ng == 1) {
        const int slab = (mg * 2 + og) * 2048;
        #pragma unroll
        for (int mi = 0; mi < 2; ++mi) {
            #pragma unroll
            for (int rg = 0; rg < 4; ++rg) {
                f32x4 v = {oacc[mi][rg * 4 + 0], oacc[mi][rg * 4 + 1],
                           oacc[mi][rg * 4 + 2], oacc[mi][rg * 4 + 3]};
                *reinterpret_cast<f32x4*>(&red[slab + (mi * 4 + rg) * 256 + lane * 4]) = v;
            }
        }
    }
    __syncthreads();
    if (ng == 0) {
        const int slab = (mg * 2 + og) * 2048;
        #pragma unroll
        for (int mi = 0; mi < 2; ++mi) {
            #pragma unroll
            for (int rg = 0; rg < 4; ++rg) {
                f32x4 sum = {oacc[mi][rg * 4 + 0], oacc[mi][rg * 4 + 1],
                             oacc[mi][rg * 4 + 2], oacc[mi][rg * 4 + 3]};
                f32x4 o2 = *reinterpret_cast<const f32x4*>(
                    &red[slab + (mi * 4 + rg) * 256 + lane * 4]);
                #pragma unroll
                for (int q = 0; q < 4; ++q) sum[q] += o2[q];
                // C/D layout (m74/m101): col = lane&31, row = (r&3)+8*(r>>2)+4*hi
                #pragma unroll
                for (int q = 0; q < 4; ++q) {
                    const int row = bm0 + mg * 64 + mi * 32 + q + 8 * rg + 4 * hi;
                    out[(size_t)row * OUT + ocol] = sum[q];
                }
            }
        }
    }
}

// ---------------- fallback: fused fp32-W kernel (r2-proven) ----------------
__global__ __launch_bounds__(512) void fused_kernel(const float* __restrict__ S,
                                                    const float* __restrict__ W,
                                                    const float* __restrict__ V,
                                                    const float* __restrict__ bias,
                                                    float* __restrict__ out) {
    __shared__ unsigned short As3[128 * D];

    const int t    = threadIdx.x;
    const int lane = t & 63;
    const int w    = t >> 6;
    const int og   = w & 3;
    const int ngh  = w >> 2;
    const int l15  = lane & 15;
    const int lg   = lane >> 4;
    const int ob0  = blockIdx.x * 64;
    const int bm0  = blockIdx.y * 128;
    const int ocol = ob0 + og * 16 + l15;

    #pragma unroll
    for (int i = 0; i < (128 * D / 8) / 512; ++i) {
        int cid = i * 512 + t;
        int row = cid >> 6;
        int kc  = cid & 63;
        const float4* sp = reinterpret_cast<const float4*>(S + (size_t)(bm0 + row) * D + kc * 8);
        bf16x8 val = cvt8(sp[0], sp[1]);
        *reinterpret_cast<bf16x8*>(&As3[row * D + ((kc ^ (row & 7)) * 8)]) = val;
    }
    __syncthreads();

    f32x4 oacc[8];
    #pragma unroll
    for (int mi = 0; mi < 8; ++mi) oacc[mi] = (f32x4){0.f, 0.f, 0.f, 0.f};

    const int kofs = lg * 8;

    for (int nc = 0; nc < 8; ++nc) {
        const int n0 = ngh * 32 + nc * 4;

        f32x4 pre[4][8];
        #pragma unroll
        for (int j = 0; j < 4; ++j)
            #pragma unroll
            for (int mi = 0; mi < 8; ++mi) pre[j][mi] = (f32x4){0.f, 0.f, 0.f, 0.f};

        float cacc[4] = {0.f, 0.f, 0.f, 0.f};

        const float* wbase = W + ((size_t)n0 * OUT + ocol) * D + kofs;
        const float* vbase = V + (size_t)n0 * D + kofs;

        #pragma unroll 2
        for (int ks = 0; ks < 16; ++ks) {
            bf16x8 bq[4];
            #pragma unroll
            for (int j = 0; j < 4; ++j) {
                const float* wr = wbase + (size_t)j * (OUT * D) + ks * 32;
                float4 wa = *reinterpret_cast<const float4*>(wr);
                float4 wb = *reinterpret_cast<const float4*>(wr + 4);
                const float* vr = vbase + (size_t)j * D + ks * 32;
                float4 va = *reinterpret_cast<const float4*>(vr);
                float4 vb = *reinterpret_cast<const float4*>(vr + 4);
                cacc[j] += wa.x * va.x + wa.y * va.y + wa.z * va.z + wa.w * va.w
                         + wb.x * vb.x + wb.y * vb.y + wb.z * vb.z + wb.w * vb.w;
                bq[j] = cvt8(wa, wb);
            }
            const int kc = ks * 4 + lg;
            #pragma unroll
            for (int mi = 0; mi < 8; ++mi) {
                const int row = mi * 16 + l15;
                bf16x8 aq = *reinterpret_cast<const bf16x8*>(
                    &As3[row * D + ((kc ^ (row & 7)) * 8)]);
                pre[0][mi] = __builtin_amdgcn_mfma_f32_16x16x32_bf16(aq, bq[0], pre[0][mi], 0, 0, 0);
                pre[1][mi] = __builtin_amdgcn_mfma_f32_16x16x32_bf16(aq, bq[1], pre[1][mi], 0, 0, 0);
                pre[2][mi] = __builtin_amdgcn_mfma_f32_16x16x32_bf16(aq, bq[2], pre[2][mi], 0, 0, 0);
                pre[3][mi] = __builtin_amdgcn_mfma_f32_16x16x32_bf16(aq, bq[3], pre[3][mi], 0, 0, 0);
            }
        }

        #pragma unroll
        for (int j = 0; j < 4; ++j) {
            float cs = cacc[j];
            cs += __shfl_xor(cs, 16);
            cs += __shfl_xor(cs, 32);
            const float cv = bias[(n0 + j) * OUT + ocol] - cs;
            #pragma unroll
            for (int mi = 0; mi < 8; ++mi)
                #pragma unroll
                for (int r = 0; r < 4; ++r)
                    oacc[mi][r] += fmaxf(pre[j][mi][r] + cv, 0.f);
        }
    }

    __syncthreads();
    float* red = reinterpret_cast<float*>(As3);
    if (ngh == 1) {
        #pragma unroll
        for (int mi = 0; mi < 8; ++mi)
            *reinterpret_cast<f32x4*>(&red[(og * 8 + mi) * 256 + lane * 4]) = oacc[mi];
    }
    __syncthreads();
    if (ngh == 0) {
        #pragma unroll
        for (int mi = 0; mi < 8; ++mi) {
            f32x4 o2 = *reinterpret_cast<const f32x4*>(&red[(og * 8 + mi) * 256 + lane * 4]);
            #pragma unroll
            for (int r = 0; r < 4; ++r) {
                int row = bm0 + mi * 16 + lg * 4 + r;
                out[(size_t)row * OUT + ocol] = oacc[mi][r] + o2[r];
            }
        }
    }
}

extern "C" void kernel_launch(void* const* d_in, const int* in_sizes, int n_in,
                              void* d_out, int out_size, void* d_ws, size_t ws_size,
                              hipStream_t stream) {
    const float* S    = (const float*)d_in[0];   // semantic_vec [B, D]
    const float* V    = (const float*)d_in[1];   // vertices     [N, D]
    const float* W    = (const float*)d_in[2];   // W            [N, OUT, D]
    const float* bias = (const float*)d_in[3];   // b            [N, OUT]
    float* out = (float*)d_out;                  // [B, OUT] f32

    const size_t wb_bytes = (size_t)N * OUT * D * sizeof(unsigned short); // 128 MiB
    const size_t c_bytes  = (size_t)N * OUT * sizeof(float);              // 512 KiB

    if (ws_size >= wb_bytes + c_bytes) {
        unsigned short* Wswz = (unsigned short*)d_ws;
        float*          c    = (float*)((char*)d_ws + wb_bytes);
        prep_kernel<<<dim3(N * 32), dim3(256), 0, stream>>>(W, V, bias, Wswz, c);
        main_kernel<<<dim3(OUT / BO, B / BM), dim3(TPB), 0, stream>>>(S, Wswz, c, out);
    } else {
        fused_kernel<<<dim3(OUT / 64, B / 128), dim3(512), 0, stream>>>(S, W, V, bias, out);
    }
}